// Round 4
// baseline (139.740 us; speedup 1.0000x reference)
//
#include <hip/hip_runtime.h>

#define N_VOX 32768
#define CCH 128
#define EPSV 1e-5f

typedef __attribute__((ext_vector_type(8))) short bfrag;
typedef __attribute__((ext_vector_type(4))) float ffrag;

__device__ __forceinline__ float bf2f_lo(unsigned int u) {
    union { unsigned int i; float f; } c; c.i = u << 16; return c.f;
}
__device__ __forceinline__ float bf2f_hi(unsigned int u) {
    union { unsigned int i; float f; } c; c.i = u & 0xFFFF0000u; return c.f;
}
__device__ __forceinline__ unsigned short f2bf(float f) {
    union { float f; unsigned int i; } c; c.f = f;
    unsigned int i = c.i;
    return (unsigned short)((i + 0x7FFFu + ((i >> 16) & 1u)) >> 16);
}

// -------- Kernel 0: convert weights fp32 -> bf16 (once per launch) --------
// wq: 384*128 elems, wp: 128*128 elems.
__global__ __launch_bounds__(256) void convw_kernel(const float* __restrict__ qkv_w,
                                                    const float* __restrict__ proj_w,
                                                    unsigned short* __restrict__ wq,
                                                    unsigned short* __restrict__ wp) {
    int i = (blockIdx.x * 256 + threadIdx.x) * 4;
    if (i < 384 * 128) {
        float4 v = *(const float4*)&qkv_w[i];
        ushort4 pk;
        pk.x = f2bf(v.x); pk.y = f2bf(v.y); pk.z = f2bf(v.z); pk.w = f2bf(v.w);
        *(ushort4*)&wq[i] = pk;
    } else {
        int j = i - 384 * 128;
        float4 v = *(const float4*)&proj_w[j];
        ushort4 pk;
        pk.x = f2bf(v.x); pk.y = f2bf(v.y); pk.z = f2bf(v.z); pk.w = f2bf(v.w);
        *(ushort4*)&wp[j] = pk;
    }
}

// -------- Kernel 1: fused LayerNorm + QKV GEMM --------
// Block: 64 voxels. LN x(C,N) tile -> a_s (64x128 bf16), then loop 6 o-tiles.
__global__ __launch_bounds__(256) void ln_qkv_kernel(const float* __restrict__ x,
                                                     const float* __restrict__ gamma,
                                                     const float* __restrict__ beta,
                                                     const unsigned short* __restrict__ wq,
                                                     const float* __restrict__ bias,
                                                     unsigned short* __restrict__ qkv) {
    __shared__ __align__(16) unsigned short a_s[64 * 136];
    __shared__ __align__(16) char pool[128 * 65 * 4];   // xs (float) then b_s (bf16)
    __shared__ float g[128], b[128];
    __shared__ float ps[256], pq[256];
    __shared__ float muS[64], rsS[64];
    float* xs = (float*)pool;
    unsigned short* b_s = (unsigned short*)pool;

    int t = threadIdx.x;
    int v0 = blockIdx.x * 64;
    if (t < 128) { g[t] = gamma[t]; b[t] = beta[t]; }
    int vv = t & 63, cq = t >> 6;
    for (int cb = 0; cb < 32; cb++) {
        int c = cb * 4 + cq;
        xs[c * 65 + vv] = x[(size_t)c * N_VOX + v0 + vv];
    }
    __syncthreads();
    float s = 0.f, sq = 0.f;
    for (int i = 0; i < 32; i++) {
        float val = xs[(cq * 32 + i) * 65 + vv];
        s += val; sq += val * val;
    }
    ps[t] = s; pq[t] = sq;
    __syncthreads();
    if (t < 64) {
        float S = ps[t] + ps[t + 64] + ps[t + 128] + ps[t + 192];
        float Q = pq[t] + pq[t + 64] + pq[t + 128] + pq[t + 192];
        float mu = S * (1.0f / 128.0f);
        float var = Q * (1.0f / 128.0f) - mu * mu;
        muS[t] = mu; rsS[t] = rsqrtf(var + EPSV);
    }
    __syncthreads();
    {
        int c8 = t & 15;
        #pragma unroll
        for (int pass = 0; pass < 4; pass++) {
            int v = pass * 16 + (t >> 4);
            float mu = muS[v], rs = rsS[v];
            union { unsigned short u[8]; uint4 q; } pk;
            #pragma unroll
            for (int i = 0; i < 8; i++) {
                int c = c8 * 8 + i;
                float val = (xs[c * 65 + v] - mu) * rs * g[c] + b[c];
                pk.u[i] = f2bf(val);
            }
            *(uint4*)&a_s[v * 136 + c8 * 8] = pk.q;
        }
    }
    __syncthreads();   // xs reads done; pool may be reused as b_s

    int wvi = t >> 6, lane = t & 63, m = lane & 15, quad = lane >> 4;
    int r4 = t >> 4, c8 = t & 15;

    for (int ot = 0; ot < 6; ot++) {
        int o0 = ot * 64;
        #pragma unroll
        for (int pass = 0; pass < 4; pass++) {
            int r = pass * 16 + r4;
            *(uint4*)&b_s[r * 136 + c8 * 8] =
                *(const uint4*)&wq[(size_t)(o0 + r) * 128 + c8 * 8];
        }
        __syncthreads();
        ffrag acc[4] = {ffrag{0,0,0,0}, ffrag{0,0,0,0}, ffrag{0,0,0,0}, ffrag{0,0,0,0}};
        #pragma unroll
        for (int kk = 0; kk < 4; kk++) {
            bfrag a = *(bfrag*)&a_s[(wvi * 16 + m) * 136 + kk * 32 + quad * 8];
            #pragma unroll
            for (int nt = 0; nt < 4; nt++) {
                bfrag bb = *(bfrag*)&b_s[(nt * 16 + m) * 136 + kk * 32 + quad * 8];
                acc[nt] = __builtin_amdgcn_mfma_f32_16x16x32_bf16(a, bb, acc[nt], 0, 0, 0);
            }
        }
        #pragma unroll
        for (int nt = 0; nt < 4; nt++) {
            int o = o0 + nt * 16 + m;
            float bs = bias[o];
            int sec = o >> 7;
            int oc = o & 127;
            unsigned short* dst = qkv + (size_t)sec * ((size_t)N_VOX * 128);
            #pragma unroll
            for (int r = 0; r < 4; r++) {
                int vg = v0 + wvi * 16 + quad * 4 + r;
                dst[(size_t)vg * 128 + oc] = f2bf(acc[nt][r] + bs);
            }
        }
        __syncthreads();   // before overwriting b_s next iteration
    }
}

// -------- Kernel 2: neighborhood attention (packed 2 channels/lane) --------
// Lane l owns channels {2l, 2l+1}; head = l>>4; reduction group = 16 lanes.
// ob may alias qb (each lane reads q[v] before writing o[v] at same address).
__global__ __launch_bounds__(256) void attn_kernel(const unsigned int* __restrict__ qb,
                                                   const unsigned int* __restrict__ kb,
                                                   const unsigned int* __restrict__ vb,
                                                   unsigned int* __restrict__ ob) {
    int t = threadIdx.x;
    int wave = t >> 6, lane = t & 63;
    int v = blockIdx.x * 4 + wave;
    int z = v & 31, y = (v >> 5) & 31, x = v >> 10;
    int sx = min(max(x - 1, 0), 29);
    int sy = min(max(y - 1, 0), 29);
    int sz = min(max(z - 1, 0), 29);
    int base = (sx << 10) + (sy << 5) + sz;
    const float scale = 0.17677669529663687f; // 32^-0.5
    unsigned int qpk = qb[(size_t)v * 64 + lane];
    float q0 = bf2f_lo(qpk) * scale;
    float q1 = bf2f_hi(qpk) * scale;
    float s[27];
    unsigned int vpk[27];
    #pragma unroll
    for (int j = 0; j < 27; j++) {
        int jx = j / 9, jy = (j % 9) / 3, jz = j % 3;
        int vj = base + (jx << 10) + (jy << 5) + jz;
        size_t idx = (size_t)vj * 64 + lane;
        unsigned int kpk = kb[idx];
        vpk[j] = vb[idx];
        float p = q0 * bf2f_lo(kpk) + q1 * bf2f_hi(kpk);
        p += __shfl_xor(p, 8);
        p += __shfl_xor(p, 4);
        p += __shfl_xor(p, 2);
        p += __shfl_xor(p, 1);
        s[j] = p;
    }
    float mx = s[0];
    #pragma unroll
    for (int j = 1; j < 27; j++) mx = fmaxf(mx, s[j]);
    float sum = 0.f;
    #pragma unroll
    for (int j = 0; j < 27; j++) { s[j] = __expf(s[j] - mx); sum += s[j]; }
    float inv = 1.0f / sum;
    float o0 = 0.f, o1 = 0.f;
    #pragma unroll
    for (int j = 0; j < 27; j++) {
        o0 += s[j] * bf2f_lo(vpk[j]);
        o1 += s[j] * bf2f_hi(vpk[j]);
    }
    unsigned int opk = ((unsigned int)f2bf(o0 * inv)) | (((unsigned int)f2bf(o1 * inv)) << 16);
    ob[(size_t)v * 64 + lane] = opk;
}

// -------- Kernel 3: proj GEMM + bias + residual + transpose to (C, N) --------
// Stages A once, loops both 64-col o-tiles. B from pre-converted bf16 wp.
__global__ __launch_bounds__(256) void proj_gemm(const unsigned short* __restrict__ a,
                                                 const unsigned short* __restrict__ wp,
                                                 const float* __restrict__ bias,
                                                 const float* __restrict__ xres,
                                                 float* __restrict__ out) {
    __shared__ __align__(16) unsigned short a_s[64 * 136];
    __shared__ __align__(16) unsigned short b_s[64 * 136];
    int t = threadIdx.x;
    int m0 = blockIdx.x * 64;
    int r4 = t >> 4, c8 = t & 15;
    #pragma unroll
    for (int pass = 0; pass < 4; pass++) {
        int r = pass * 16 + r4;
        *(uint4*)&a_s[r * 136 + c8 * 8] =
            *(const uint4*)&a[(size_t)(m0 + r) * 128 + c8 * 8];
    }
    int wvi = t >> 6, lane = t & 63, m = lane & 15, quad = lane >> 4;

    for (int ot = 0; ot < 2; ot++) {
        int o0 = ot * 64;
        #pragma unroll
        for (int pass = 0; pass < 4; pass++) {
            int r = pass * 16 + r4;
            *(uint4*)&b_s[r * 136 + c8 * 8] =
                *(const uint4*)&wp[(size_t)(o0 + r) * 128 + c8 * 8];
        }
        __syncthreads();
        ffrag acc[4] = {ffrag{0,0,0,0}, ffrag{0,0,0,0}, ffrag{0,0,0,0}, ffrag{0,0,0,0}};
        #pragma unroll
        for (int kk = 0; kk < 4; kk++) {
            bfrag av = *(bfrag*)&a_s[(wvi * 16 + m) * 136 + kk * 32 + quad * 8];
            #pragma unroll
            for (int nt = 0; nt < 4; nt++) {
                bfrag bb = *(bfrag*)&b_s[(nt * 16 + m) * 136 + kk * 32 + quad * 8];
                acc[nt] = __builtin_amdgcn_mfma_f32_16x16x32_bf16(av, bb, acc[nt], 0, 0, 0);
            }
        }
        #pragma unroll
        for (int nt = 0; nt < 4; nt++) {
            int o = o0 + nt * 16 + m;
            float bs = bias[o];
            int vg = m0 + wvi * 16 + quad * 4;
            float4 r = *(const float4*)&xres[(size_t)o * N_VOX + vg];
            float4 ov;
            ov.x = acc[nt][0] + bs + r.x;
            ov.y = acc[nt][1] + bs + r.y;
            ov.z = acc[nt][2] + bs + r.z;
            ov.w = acc[nt][3] + bs + r.w;
            *(float4*)&out[(size_t)o * N_VOX + vg] = ov;
        }
        __syncthreads();
    }
}

extern "C" void kernel_launch(void* const* d_in, const int* in_sizes, int n_in,
                              void* d_out, int out_size, void* d_ws, size_t ws_size,
                              hipStream_t stream) {
    const float* x      = (const float*)d_in[0];
    const float* gamma  = (const float*)d_in[1];
    const float* beta   = (const float*)d_in[2];
    const float* qkv_w  = (const float*)d_in[3];
    const float* qkv_b  = (const float*)d_in[4];
    const float* proj_w = (const float*)d_in[5];
    const float* proj_b = (const float*)d_in[6];
    float* out = (float*)d_out;

    // ws layout: [0, 128KB) bf16 weights; [8MB, 32MB) qkv (q|k|v, 8MB each).
    // attn output overwrites the q region (safe: per-lane read-before-write).
    unsigned short* wq   = (unsigned short*)d_ws;                          // 96 KB
    unsigned short* wp   = wq + 384 * 128;                                 // 32 KB
    unsigned short* qkv  = (unsigned short*)((char*)d_ws + (8u << 20));
    unsigned short* qb   = qkv;
    unsigned short* kb   = qkv + (size_t)N_VOX * 128;
    unsigned short* vb   = qkv + (size_t)2 * N_VOX * 128;
    unsigned short* attn = qb;   // alias

    hipLaunchKernelGGL(convw_kernel, dim3(64), dim3(256), 0, stream, qkv_w, proj_w, wq, wp);
    hipLaunchKernelGGL(ln_qkv_kernel, dim3(512), dim3(256), 0, stream, x, gamma, beta, wq, qkv_b, qkv);
    hipLaunchKernelGGL(attn_kernel, dim3(8192), dim3(256), 0, stream,
                       (const unsigned int*)qb, (const unsigned int*)kb,
                       (const unsigned int*)vb, (unsigned int*)attn);
    hipLaunchKernelGGL(proj_gemm, dim3(512), dim3(256), 0, stream, attn, wp, proj_b, x, out);
}